// Round 5
// baseline (2173.453 us; speedup 1.0000x reference)
//
#include <hip/hip_runtime.h>

#define NN 50000
#define NE 800000
#define INC 128
#define HIDC 64
#define NL 14
#define EPS_MSG 1e-7f
#define EPS_SM 1e-16f
#define LN_EPS 1e-5f

#define SCAN_B 256
#define NB_SCAN ((NN + SCAN_B - 1) / SCAN_B)   // 196

__device__ __forceinline__ float wave_sum(float v) {
    #pragma unroll
    for (int o = 32; o > 0; o >>= 1) v += __shfl_xor(v, o, 64);
    return v;
}
__device__ __forceinline__ float wave_max(float v) {
    #pragma unroll
    for (int o = 32; o > 0; o >>= 1) v = fmaxf(v, __shfl_xor(v, o, 64));
    return v;
}
// pack two floats to bf16 pair (RTNE), lo in low half
__device__ __forceinline__ unsigned pack_bf2(float lo, float hi) {
    unsigned ul = __float_as_uint(lo); ul += 0x7fffu + ((ul >> 16) & 1u);
    unsigned uh = __float_as_uint(hi); uh += 0x7fffu + ((uh >> 16) & 1u);
    return (ul >> 16) | (uh & 0xffff0000u);
}

// ---------------- CSR build ----------------
__global__ void k_hist(const int* __restrict__ dst, int* __restrict__ deg) {
    int i = blockIdx.x * blockDim.x + threadIdx.x;
    if (i < NE) atomicAdd(&deg[dst[i]], 1);
}

__global__ void k_part(const int* __restrict__ deg, int* __restrict__ part) {
    __shared__ int sm[SCAN_B];
    int b = blockIdx.x;
    int i = b * SCAN_B + threadIdx.x;
    sm[threadIdx.x] = (i < NN) ? deg[i] : 0;
    __syncthreads();
    for (int s = SCAN_B / 2; s > 0; s >>= 1) {
        if (threadIdx.x < s) sm[threadIdx.x] += sm[threadIdx.x + s];
        __syncthreads();
    }
    if (threadIdx.x == 0) part[b] = sm[0];
}

__global__ void k_scanpart(const int* __restrict__ part, int* __restrict__ partOfs) {
    __shared__ int sm[SCAN_B];
    int t = threadIdx.x;
    int own = (t < NB_SCAN) ? part[t] : 0;
    sm[t] = own;
    __syncthreads();
    for (int o = 1; o < SCAN_B; o <<= 1) {
        int v = (t >= o) ? sm[t - o] : 0;
        __syncthreads();
        sm[t] += v;
        __syncthreads();
    }
    if (t < NB_SCAN) partOfs[t] = sm[t] - own;   // exclusive
}

__global__ void k_scanfinal(const int* __restrict__ deg, const int* __restrict__ partOfs,
                            int* __restrict__ rowOfs) {
    __shared__ int sm[SCAN_B];
    int b = blockIdx.x, t = threadIdx.x;
    int i = b * SCAN_B + t;
    int d = (i < NN) ? deg[i] : 0;
    sm[t] = d;
    __syncthreads();
    for (int o = 1; o < SCAN_B; o <<= 1) {
        int v = (t >= o) ? sm[t - o] : 0;
        __syncthreads();
        sm[t] += v;
        __syncthreads();
    }
    if (i < NN) rowOfs[i] = partOfs[b] + sm[t] - d;
    if (i == 0) rowOfs[NN] = NE;
}

__global__ void k_scatter(const int* __restrict__ src, const int* __restrict__ dst,
                          const int* __restrict__ rowOfs, int* __restrict__ cur,
                          int* __restrict__ csr) {
    int i = blockIdx.x * blockDim.x + threadIdx.x;
    if (i < NE) {
        int d = dst[i];
        int p = rowOfs[d] + atomicAdd(&cur[d], 1);
        csr[p] = src[i];
    }
}

// ---- encoder: h = x @ encW + encb ; LDS-tiled, emits fp32 h + bf16-pair table
__global__ __launch_bounds__(256) void k_enc(const float* __restrict__ x,
                                             const float* __restrict__ W,
                                             const float* __restrict__ bias,
                                             float* __restrict__ h,
                                             unsigned* __restrict__ B0) {
    __shared__ float XL[32 * INC];     // 16 KB
    __shared__ float WL[INC * HIDC];   // 32 KB
    int tid = threadIdx.x;
    for (int i = tid; i < (INC * HIDC) / 4; i += 256)
        ((float4*)WL)[i] = ((const float4*)W)[i];
    int r0 = blockIdx.x * 32;
    for (int i = tid; i < (32 * INC) / 4; i += 256) {
        int row = i >> 5;            // 32 float4 per row
        float4 val = make_float4(0.f, 0.f, 0.f, 0.f);
        if (r0 + row < NN) val = ((const float4*)x)[(size_t)(r0 + row) * 32 + (i & 31)];
        ((float4*)XL)[i] = val;
    }
    __syncthreads();
    int lane = tid & 63, w = tid >> 6;
    float bv = bias[lane];
    #pragma unroll
    for (int i = 0; i < 4; i++) {
        int ra = w * 8 + i * 2, rb = ra + 1;
        float a0 = 0.f, a1 = 0.f, a2 = 0.f, a3 = 0.f;
        float c0 = 0.f, c1 = 0.f, c2 = 0.f, c3 = 0.f;
        #pragma unroll
        for (int k = 0; k < INC; k += 4) {
            float4 xa = *(const float4*)&XL[ra * INC + k];
            float4 xb = *(const float4*)&XL[rb * INC + k];
            float w0 = WL[(k + 0) * HIDC + lane];
            float w1 = WL[(k + 1) * HIDC + lane];
            float w2 = WL[(k + 2) * HIDC + lane];
            float w3 = WL[(k + 3) * HIDC + lane];
            a0 = fmaf(xa.x, w0, a0); a1 = fmaf(xa.y, w1, a1);
            a2 = fmaf(xa.z, w2, a2); a3 = fmaf(xa.w, w3, a3);
            c0 = fmaf(xb.x, w0, c0); c1 = fmaf(xb.y, w1, c1);
            c2 = fmaf(xb.z, w2, c2); c3 = fmaf(xb.w, w3, c3);
        }
        int ga = r0 + ra, gb = r0 + rb;
        float va = bv + ((a0 + a1) + (a2 + a3));
        float vb = bv + ((c0 + c1) + (c2 + c3));
        float pa = __shfl_xor(va, 1, 64);
        float pb = __shfl_xor(vb, 1, 64);
        if (ga < NN) {
            h[(size_t)ga * HIDC + lane] = va;
            if (!(lane & 1)) B0[(size_t)ga * 32 + (lane >> 1)] = pack_bf2(va, pa);
        }
        if (gb < NN) {
            h[(size_t)gb * HIDC + lane] = vb;
            if (!(lane & 1)) B0[(size_t)gb * 32 + (lane >> 1)] = pack_bf2(vb, pb);
        }
    }
}

// ---- fused layer: bf16-pair gather softmax-aggr + self(LN recompute) +
//      (aggr+y)@W+b (+res) + epilogue (carry + next bf16 table | final logsoftmax)
// 3125 blocks x 256: wave handles nodes 4w..4w+3
template<bool FIRST, bool FINAL>
__global__ __launch_bounds__(256) void k_layer(const float* __restrict__ henc,
                                               float* __restrict__ h,
                                               const unsigned* __restrict__ Bin,
                                               unsigned* __restrict__ Bout,
                                               const int* __restrict__ rowOfs,
                                               const int* __restrict__ csr,
                                               const float* __restrict__ W,
                                               const float* __restrict__ b,
                                               const float* __restrict__ tptr) {
    __shared__ float WL[HIDC * HIDC];  // 16 KB
    for (int i = threadIdx.x; i < (HIDC * HIDC) / 4; i += 256)
        ((float4*)WL)[i] = ((const float4*)W)[i];
    __syncthreads();   // early: waves decoupled for the whole gather phase

    int lane = threadIdx.x & 63;
    int wid = (blockIdx.x * 256 + threadIdx.x) >> 6;   // [0, 12500)
    int half = lane >> 5, c2 = lane & 31;
    float t = *tptr;
    float tl = t * 1.44269504088896f;   // t * log2(e)
    float bv = b[lane];

    #pragma unroll 1
    for (int i = 0; i < 4; i++) {
        int v = wid * 4 + i;
        int e0 = rowOfs[v], e1 = rowOfs[v + 1];
        float se0 = 0.f, se1 = 0.f, sw0 = 0.f, sw1 = 0.f;
        for (int e = e0; e < e1; e += 16) {
            #pragma unroll
            for (int j = 0; j < 8; j++) {
                int ee = e + 2 * j + half;
                bool valid = ee < e1;
                int s = csr[valid ? ee : e0];
                unsigned q = Bin[(size_t)s * 32 + c2];
                float glo = __uint_as_float(q << 16);
                float ghi = __uint_as_float(q & 0xffff0000u);
                glo = fmaxf(glo, 0.f) + EPS_MSG;
                ghi = fmaxf(ghi, 0.f) + EPS_MSG;
                float wlo = valid ? exp2f(tl * glo) : 0.f;
                float whi = valid ? exp2f(tl * ghi) : 0.f;
                se0 += wlo; sw0 = fmaf(glo, wlo, sw0);
                se1 += whi; sw1 = fmaf(ghi, whi, sw1);
            }
        }
        // combine edge-halves, then redistribute channel pairs to 64 lanes
        se0 += __shfl_xor(se0, 32, 64); sw0 += __shfl_xor(sw0, 32, 64);
        se1 += __shfl_xor(se1, 32, 64); sw1 += __shfl_xor(sw1, 32, 64);
        float seA = __shfl(se0, lane >> 1, 64), seB = __shfl(se1, lane >> 1, 64);
        float swA = __shfl(sw0, lane >> 1, 64), swB = __shfl(sw1, lane >> 1, 64);
        float se = (lane & 1) ? seB : seA;
        float sw = (lane & 1) ? swB : swA;
        float aggr = sw / (se + EPS_SM);

        float base = bv;
        float self;
        if (FIRST) {
            self = henc[(size_t)v * HIDC + lane];
        } else {
            float hv = h[(size_t)v * HIDC + lane];
            float mu = wave_sum(hv) * (1.f / 64.f);
            float d = hv - mu;
            float var = wave_sum(d * d) * (1.f / 64.f);
            self = fmaxf(d * rsqrtf(var + LN_EPS), 0.f);
            base += hv;
        }
        float a = aggr + self;
        float a0 = 0.f, a1 = 0.f, a2 = 0.f, a3 = 0.f;
        #pragma unroll
        for (int k = 0; k < 64; k += 4) {
            a0 = fmaf(__shfl(a, k, 64),     WL[k * HIDC + lane],       a0);
            a1 = fmaf(__shfl(a, k + 1, 64), WL[(k + 1) * HIDC + lane], a1);
            a2 = fmaf(__shfl(a, k + 2, 64), WL[(k + 2) * HIDC + lane], a2);
            a3 = fmaf(__shfl(a, k + 3, 64), WL[(k + 3) * HIDC + lane], a3);
        }
        float acc = base + ((a0 + a1) + (a2 + a3));

        if (FINAL) {
            float mu = wave_sum(acc) * (1.f / 64.f);
            float d = acc - mu;
            float var = wave_sum(d * d) * (1.f / 64.f);
            float z = fmaxf(d * rsqrtf(var + LN_EPS), 0.f);
            float m = wave_max(z);
            float s2 = wave_sum(exp2f((z - m) * 1.44269504088896f));
            h[(size_t)v * HIDC + lane] = z - (m + __logf(s2));
        } else {
            h[(size_t)v * HIDC + lane] = acc;
            float mu = wave_sum(acc) * (1.f / 64.f);
            float d = acc - mu;
            float var = wave_sum(d * d) * (1.f / 64.f);
            float y = fmaxf(d * rsqrtf(var + LN_EPS), 0.f);
            float yp = __shfl_xor(y, 1, 64);
            if (!(lane & 1)) Bout[(size_t)v * 32 + (lane >> 1)] = pack_bf2(y, yp);
        }
    }
}

extern "C" void kernel_launch(void* const* d_in, const int* in_sizes, int n_in,
                              void* d_out, int out_size, void* d_ws, size_t ws_size,
                              hipStream_t stream) {
    const float* x    = (const float*)d_in[0];
    const int*   ei   = (const int*)d_in[1];
    const float* encW = (const float*)d_in[2];
    const float* encb = (const float*)d_in[3];
    const float* mlpW = (const float*)d_in[4];
    const float* mlpb = (const float*)d_in[5];
    const float* t    = (const float*)d_in[6];

    float* h = (float*)d_out;   // residual carry, doubles as final output

    char* ws = (char*)d_ws;
    size_t off = 0;
    auto alloc = [&](size_t bytes) -> void* {
        void* p = ws + off;
        off += (bytes + 255) / 256 * 256;
        return p;
    };
    float*    henc   = (float*)alloc((size_t)NN * HIDC * 4);
    unsigned* B0     = (unsigned*)alloc((size_t)NN * 32 * 4);
    unsigned* B1     = (unsigned*)alloc((size_t)NN * 32 * 4);
    int*      deg    = (int*)alloc((size_t)NN * 4);
    int*      cur    = (int*)alloc((size_t)NN * 4);
    int*      rowOfs = (int*)alloc((size_t)(NN + 1) * 4);
    int*      part   = (int*)alloc((size_t)NB_SCAN * 4);
    int*      partOf = (int*)alloc((size_t)NB_SCAN * 4);
    int*      csr    = (int*)alloc((size_t)NE * 4);

    const int* src = ei;
    const int* dst = ei + NE;

    hipMemsetAsync(deg, 0, (size_t)NN * 4, stream);
    hipMemsetAsync(cur, 0, (size_t)NN * 4, stream);

    k_hist<<<(NE + 255) / 256, 256, 0, stream>>>(dst, deg);
    k_part<<<NB_SCAN, SCAN_B, 0, stream>>>(deg, part);
    k_scanpart<<<1, SCAN_B, 0, stream>>>(part, partOf);
    k_scanfinal<<<NB_SCAN, SCAN_B, 0, stream>>>(deg, partOf, rowOfs);
    k_scatter<<<(NE + 255) / 256, 256, 0, stream>>>(src, dst, rowOfs, cur, csr);

    k_enc<<<(NN + 31) / 32, 256, 0, stream>>>(x, encW, encb, henc, B0);

    // layer 0: self from henc fp32, messages from B0; no residual; emit B1
    k_layer<true, false><<<3125, 256, 0, stream>>>(henc, h, B0, B1, rowOfs, csr,
                                                   mlpW, mlpb, t);
    for (int l = 1; l < NL - 1; l++) {
        const float* W  = mlpW + (size_t)l * HIDC * HIDC;
        const float* bb = mlpb + (size_t)l * HIDC;
        unsigned* Bi = (l & 1) ? B1 : B0;
        unsigned* Bo = (l & 1) ? B0 : B1;
        k_layer<false, false><<<3125, 256, 0, stream>>>(nullptr, h, Bi, Bo, rowOfs, csr,
                                                        W, bb, t + l);
    }
    // layer 13 (odd): reads B1; fused final LN + relu + log_softmax
    k_layer<false, true><<<3125, 256, 0, stream>>>(nullptr, h, B1, nullptr, rowOfs, csr,
                                                   mlpW + (size_t)(NL - 1) * HIDC * HIDC,
                                                   mlpb + (size_t)(NL - 1) * HIDC,
                                                   t + (NL - 1));
}

// Round 6
// 1236.591 us; speedup vs baseline: 1.7576x; 1.7576x over previous
//
#include <hip/hip_runtime.h>

#define NN 50000
#define NE 800000
#define INC 128
#define HIDC 64
#define NL 14
#define EPS_MSG 1e-7f
#define EPS_SM 1e-16f
#define LN_EPS 1e-5f

#define SCAN_B 256
#define NB_SCAN ((NN + SCAN_B - 1) / SCAN_B)   // 196

__device__ __forceinline__ float wave_sum(float v) {
    #pragma unroll
    for (int o = 32; o > 0; o >>= 1) v += __shfl_xor(v, o, 64);
    return v;
}
__device__ __forceinline__ float wave_max(float v) {
    #pragma unroll
    for (int o = 32; o > 0; o >>= 1) v = fmaxf(v, __shfl_xor(v, o, 64));
    return v;
}
// pack two floats to bf16 pair (RTNE), lo in low half
__device__ __forceinline__ unsigned pack_bf2(float lo, float hi) {
    unsigned ul = __float_as_uint(lo); ul += 0x7fffu + ((ul >> 16) & 1u);
    unsigned uh = __float_as_uint(hi); uh += 0x7fffu + ((uh >> 16) & 1u);
    return (ul >> 16) | (uh & 0xffff0000u);
}

// ---------------- CSR build ----------------
__global__ void k_hist(const int* __restrict__ dst, int* __restrict__ deg) {
    int i = blockIdx.x * blockDim.x + threadIdx.x;
    if (i < NE) atomicAdd(&deg[dst[i]], 1);
}

__global__ void k_part(const int* __restrict__ deg, int* __restrict__ part) {
    __shared__ int sm[SCAN_B];
    int b = blockIdx.x;
    int i = b * SCAN_B + threadIdx.x;
    sm[threadIdx.x] = (i < NN) ? deg[i] : 0;
    __syncthreads();
    for (int s = SCAN_B / 2; s > 0; s >>= 1) {
        if (threadIdx.x < s) sm[threadIdx.x] += sm[threadIdx.x + s];
        __syncthreads();
    }
    if (threadIdx.x == 0) part[b] = sm[0];
}

__global__ void k_scanpart(const int* __restrict__ part, int* __restrict__ partOfs) {
    __shared__ int sm[SCAN_B];
    int t = threadIdx.x;
    int own = (t < NB_SCAN) ? part[t] : 0;
    sm[t] = own;
    __syncthreads();
    for (int o = 1; o < SCAN_B; o <<= 1) {
        int v = (t >= o) ? sm[t - o] : 0;
        __syncthreads();
        sm[t] += v;
        __syncthreads();
    }
    if (t < NB_SCAN) partOfs[t] = sm[t] - own;   // exclusive
}

__global__ void k_scanfinal(const int* __restrict__ deg, const int* __restrict__ partOfs,
                            int* __restrict__ rowOfs) {
    __shared__ int sm[SCAN_B];
    int b = blockIdx.x, t = threadIdx.x;
    int i = b * SCAN_B + t;
    int d = (i < NN) ? deg[i] : 0;
    sm[t] = d;
    __syncthreads();
    for (int o = 1; o < SCAN_B; o <<= 1) {
        int v = (t >= o) ? sm[t - o] : 0;
        __syncthreads();
        sm[t] += v;
        __syncthreads();
    }
    if (i < NN) rowOfs[i] = partOfs[b] + sm[t] - d;
    if (i == 0) rowOfs[NN] = NE;
}

__global__ void k_scatter(const int* __restrict__ src, const int* __restrict__ dst,
                          const int* __restrict__ rowOfs, int* __restrict__ cur,
                          int* __restrict__ csr) {
    int i = blockIdx.x * blockDim.x + threadIdx.x;
    if (i < NE) {
        int d = dst[i];
        int p = rowOfs[d] + atomicAdd(&cur[d], 1);
        csr[p] = src[i];
    }
}

// ---- encoder: h = x @ encW + encb ; LDS-tiled, emits fp32 h + bf16-pair table
__global__ __launch_bounds__(256) void k_enc(const float* __restrict__ x,
                                             const float* __restrict__ W,
                                             const float* __restrict__ bias,
                                             float* __restrict__ h,
                                             unsigned* __restrict__ B0) {
    __shared__ float XL[32 * INC];     // 16 KB
    __shared__ float WL[INC * HIDC];   // 32 KB
    int tid = threadIdx.x;
    for (int i = tid; i < (INC * HIDC) / 4; i += 256)
        ((float4*)WL)[i] = ((const float4*)W)[i];
    int r0 = blockIdx.x * 32;
    for (int i = tid; i < (32 * INC) / 4; i += 256) {
        int row = i >> 5;            // 32 float4 per row
        float4 val = make_float4(0.f, 0.f, 0.f, 0.f);
        if (r0 + row < NN) val = ((const float4*)x)[(size_t)(r0 + row) * 32 + (i & 31)];
        ((float4*)XL)[i] = val;
    }
    __syncthreads();
    int lane = tid & 63, w = tid >> 6;
    float bv = bias[lane];
    #pragma unroll
    for (int i = 0; i < 4; i++) {
        int ra = w * 8 + i * 2, rb = ra + 1;
        float a0 = 0.f, a1 = 0.f, a2 = 0.f, a3 = 0.f;
        float c0 = 0.f, c1 = 0.f, c2 = 0.f, c3 = 0.f;
        #pragma unroll
        for (int k = 0; k < INC; k += 4) {
            float4 xa = *(const float4*)&XL[ra * INC + k];
            float4 xb = *(const float4*)&XL[rb * INC + k];
            float w0 = WL[(k + 0) * HIDC + lane];
            float w1 = WL[(k + 1) * HIDC + lane];
            float w2 = WL[(k + 2) * HIDC + lane];
            float w3 = WL[(k + 3) * HIDC + lane];
            a0 = fmaf(xa.x, w0, a0); a1 = fmaf(xa.y, w1, a1);
            a2 = fmaf(xa.z, w2, a2); a3 = fmaf(xa.w, w3, a3);
            c0 = fmaf(xb.x, w0, c0); c1 = fmaf(xb.y, w1, c1);
            c2 = fmaf(xb.z, w2, c2); c3 = fmaf(xb.w, w3, c3);
        }
        int ga = r0 + ra, gb = r0 + rb;
        float va = bv + ((a0 + a1) + (a2 + a3));
        float vb = bv + ((c0 + c1) + (c2 + c3));
        float pa = __shfl_xor(va, 1, 64);
        float pb = __shfl_xor(vb, 1, 64);
        if (ga < NN) {
            h[(size_t)ga * HIDC + lane] = va;
            if (!(lane & 1)) B0[(size_t)ga * 32 + (lane >> 1)] = pack_bf2(va, pa);
        }
        if (gb < NN) {
            h[(size_t)gb * HIDC + lane] = vb;
            if (!(lane & 1)) B0[(size_t)gb * 32 + (lane >> 1)] = pack_bf2(vb, pb);
        }
    }
}

// ---- fused layer, ONE NODE PER WAVE (12500 blocks x 256 = 50000 waves) ----
// gather: lanes split 4 edge-subgroups x 16 channel-blocks; uint2 = 4 bf16 ch
template<bool FIRST, bool FINAL>
__global__ __launch_bounds__(256) void k_layer(const float* __restrict__ henc,
                                               float* __restrict__ h,
                                               const unsigned* __restrict__ Bin,
                                               unsigned* __restrict__ Bout,
                                               const int* __restrict__ rowOfs,
                                               const int* __restrict__ csr,
                                               const float* __restrict__ W,
                                               const float* __restrict__ b,
                                               const float* __restrict__ tptr) {
    __shared__ float WL[HIDC * HIDC];  // 16 KB
    for (int i = threadIdx.x; i < (HIDC * HIDC) / 4; i += 256)
        ((float4*)WL)[i] = ((const float4*)W)[i];
    __syncthreads();   // early barrier; waves fully decoupled afterwards

    int lane = threadIdx.x & 63;
    int v = (blockIdx.x * 256 + threadIdx.x) >> 6;   // [0, 50000)
    int g = lane >> 4;          // edge subgroup 0..3
    int c = lane & 15;          // channel block (channels 4c..4c+3)
    float t = *tptr;
    float tl = t * 1.44269504088896f;   // t * log2(e)

    int e0 = rowOfs[v], e1 = rowOfs[v + 1];
    float se0 = 0.f, se1 = 0.f, se2 = 0.f, se3 = 0.f;
    float sw0 = 0.f, sw1 = 0.f, sw2 = 0.f, sw3 = 0.f;
    for (int e = e0; e < e1; e += 16) {
        #pragma unroll
        for (int j = 0; j < 4; j++) {
            int ee = e + 4 * j + g;
            bool valid = ee < e1;
            int s = csr[valid ? ee : e0];
            uint2 q = ((const uint2*)Bin)[(size_t)s * 16 + c];
            float g0 = __uint_as_float(q.x << 16);
            float g1 = __uint_as_float(q.x & 0xffff0000u);
            float g2 = __uint_as_float(q.y << 16);
            float g3 = __uint_as_float(q.y & 0xffff0000u);
            g0 = fmaxf(g0, 0.f) + EPS_MSG;
            g1 = fmaxf(g1, 0.f) + EPS_MSG;
            g2 = fmaxf(g2, 0.f) + EPS_MSG;
            g3 = fmaxf(g3, 0.f) + EPS_MSG;
            float w0 = valid ? exp2f(tl * g0) : 0.f;
            float w1 = valid ? exp2f(tl * g1) : 0.f;
            float w2 = valid ? exp2f(tl * g2) : 0.f;
            float w3 = valid ? exp2f(tl * g3) : 0.f;
            se0 += w0; sw0 = fmaf(g0, w0, sw0);
            se1 += w1; sw1 = fmaf(g1, w1, sw1);
            se2 += w2; sw2 = fmaf(g2, w2, sw2);
            se3 += w3; sw3 = fmaf(g3, w3, sw3);
        }
    }
    // reduce across the 4 edge-subgroups (lanes c, c+16, c+32, c+48) -> replicated
    #pragma unroll
    for (int m = 16; m <= 32; m <<= 1) {
        se0 += __shfl_xor(se0, m, 64); sw0 += __shfl_xor(sw0, m, 64);
        se1 += __shfl_xor(se1, m, 64); sw1 += __shfl_xor(sw1, m, 64);
        se2 += __shfl_xor(se2, m, 64); sw2 += __shfl_xor(sw2, m, 64);
        se3 += __shfl_xor(se3, m, 64); sw3 += __shfl_xor(sw3, m, 64);
    }
    float ax = sw0 / (se0 + EPS_SM);
    float ay = sw1 / (se1 + EPS_SM);
    float az = sw2 / (se2 + EPS_SM);
    float aw = sw3 / (se3 + EPS_SM);

    float base = b[lane];
    if (FIRST) {
        float4 s4 = ((const float4*)henc)[(size_t)v * 16 + c];
        ax += s4.x; ay += s4.y; az += s4.z; aw += s4.w;
    } else {
        float4 hv4 = ((const float4*)h)[(size_t)v * 16 + c];
        float ls = (hv4.x + hv4.y) + (hv4.z + hv4.w);
        #pragma unroll
        for (int m = 1; m <= 8; m <<= 1) ls += __shfl_xor(ls, m, 64);
        float mu = ls * (1.f / 64.f);
        float dx = hv4.x - mu, dy = hv4.y - mu, dz = hv4.z - mu, dw = hv4.w - mu;
        float vs = (dx * dx + dy * dy) + (dz * dz + dw * dw);
        #pragma unroll
        for (int m = 1; m <= 8; m <<= 1) vs += __shfl_xor(vs, m, 64);
        float rs = rsqrtf(vs * (1.f / 64.f) + LN_EPS);
        ax += fmaxf(dx * rs, 0.f); ay += fmaxf(dy * rs, 0.f);
        az += fmaxf(dz * rs, 0.f); aw += fmaxf(dw * rs, 0.f);
        base += h[(size_t)v * HIDC + lane];   // residual (row is L1-hot)
    }

    // GEMM: channel k = 4*(k>>2) + (k&3); component index compile-time
    float a0 = 0.f, a1 = 0.f, a2 = 0.f, a3 = 0.f;
    #pragma unroll
    for (int k = 0; k < 64; k += 4) {
        float b0 = __shfl(ax, k >> 2, 64);
        float b1 = __shfl(ay, k >> 2, 64);
        float b2 = __shfl(az, k >> 2, 64);
        float b3 = __shfl(aw, k >> 2, 64);
        a0 = fmaf(b0, WL[(k + 0) * HIDC + lane], a0);
        a1 = fmaf(b1, WL[(k + 1) * HIDC + lane], a1);
        a2 = fmaf(b2, WL[(k + 2) * HIDC + lane], a2);
        a3 = fmaf(b3, WL[(k + 3) * HIDC + lane], a3);
    }
    float acc = base + ((a0 + a1) + (a2 + a3));

    if (FINAL) {
        float mu = wave_sum(acc) * (1.f / 64.f);
        float d = acc - mu;
        float var = wave_sum(d * d) * (1.f / 64.f);
        float z = fmaxf(d * rsqrtf(var + LN_EPS), 0.f);
        float m = wave_max(z);
        float s2 = wave_sum(exp2f((z - m) * 1.44269504088896f));
        h[(size_t)v * HIDC + lane] = z - (m + __logf(s2));
    } else {
        h[(size_t)v * HIDC + lane] = acc;
        float mu = wave_sum(acc) * (1.f / 64.f);
        float d = acc - mu;
        float var = wave_sum(d * d) * (1.f / 64.f);
        float y = fmaxf(d * rsqrtf(var + LN_EPS), 0.f);
        float yp = __shfl_xor(y, 1, 64);
        if (!(lane & 1)) Bout[(size_t)v * 32 + (lane >> 1)] = pack_bf2(y, yp);
    }
}

extern "C" void kernel_launch(void* const* d_in, const int* in_sizes, int n_in,
                              void* d_out, int out_size, void* d_ws, size_t ws_size,
                              hipStream_t stream) {
    const float* x    = (const float*)d_in[0];
    const int*   ei   = (const int*)d_in[1];
    const float* encW = (const float*)d_in[2];
    const float* encb = (const float*)d_in[3];
    const float* mlpW = (const float*)d_in[4];
    const float* mlpb = (const float*)d_in[5];
    const float* t    = (const float*)d_in[6];

    float* h = (float*)d_out;   // residual carry, doubles as final output

    char* ws = (char*)d_ws;
    size_t off = 0;
    auto alloc = [&](size_t bytes) -> void* {
        void* p = ws + off;
        off += (bytes + 255) / 256 * 256;
        return p;
    };
    float*    henc   = (float*)alloc((size_t)NN * HIDC * 4);
    unsigned* B0     = (unsigned*)alloc((size_t)NN * 32 * 4);
    unsigned* B1     = (unsigned*)alloc((size_t)NN * 32 * 4);
    int*      deg    = (int*)alloc((size_t)NN * 4);
    int*      cur    = (int*)alloc((size_t)NN * 4);
    int*      rowOfs = (int*)alloc((size_t)(NN + 1) * 4);
    int*      part   = (int*)alloc((size_t)NB_SCAN * 4);
    int*      partOf = (int*)alloc((size_t)NB_SCAN * 4);
    int*      csr    = (int*)alloc((size_t)NE * 4);

    const int* src = ei;
    const int* dst = ei + NE;

    hipMemsetAsync(deg, 0, (size_t)NN * 4, stream);
    hipMemsetAsync(cur, 0, (size_t)NN * 4, stream);

    k_hist<<<(NE + 255) / 256, 256, 0, stream>>>(dst, deg);
    k_part<<<NB_SCAN, SCAN_B, 0, stream>>>(deg, part);
    k_scanpart<<<1, SCAN_B, 0, stream>>>(part, partOf);
    k_scanfinal<<<NB_SCAN, SCAN_B, 0, stream>>>(deg, partOf, rowOfs);
    k_scatter<<<(NE + 255) / 256, 256, 0, stream>>>(src, dst, rowOfs, cur, csr);

    k_enc<<<(NN + 31) / 32, 256, 0, stream>>>(x, encW, encb, henc, B0);

    // layer 0: self from henc, messages from B0; no residual; emit B1
    k_layer<true, false><<<12500, 256, 0, stream>>>(henc, h, B0, B1, rowOfs, csr,
                                                    mlpW, mlpb, t);
    for (int l = 1; l < NL - 1; l++) {
        const float* W  = mlpW + (size_t)l * HIDC * HIDC;
        const float* bb = mlpb + (size_t)l * HIDC;
        unsigned* Bi = (l & 1) ? B1 : B0;
        unsigned* Bo = (l & 1) ? B0 : B1;
        k_layer<false, false><<<12500, 256, 0, stream>>>(nullptr, h, Bi, Bo, rowOfs, csr,
                                                         W, bb, t + l);
    }
    // layer 13 (odd): reads B1; fused final LN + relu + log_softmax
    k_layer<false, true><<<12500, 256, 0, stream>>>(nullptr, h, B1, nullptr, rowOfs, csr,
                                                    mlpW + (size_t)(NL - 1) * HIDC * HIDC,
                                                    mlpb + (size_t)(NL - 1) * HIDC,
                                                    t + (NL - 1));
}

// Round 7
// 1088.895 us; speedup vs baseline: 1.9960x; 1.1356x over previous
//
#include <hip/hip_runtime.h>

#define NN 50000
#define NE 800000
#define INC 128
#define HIDC 64
#define NL 14
#define EPS_MSG 1e-7f
#define EPS_SM 1e-16f
#define LN_EPS 1e-5f

#define SCAN_B 256
#define NB_SCAN ((NN + SCAN_B - 1) / SCAN_B)   // 196

__device__ __forceinline__ float wave_sum(float v) {
    #pragma unroll
    for (int o = 32; o > 0; o >>= 1) v += __shfl_xor(v, o, 64);
    return v;
}
__device__ __forceinline__ float wave_max(float v) {
    #pragma unroll
    for (int o = 32; o > 0; o >>= 1) v = fmaxf(v, __shfl_xor(v, o, 64));
    return v;
}
__device__ __forceinline__ float bcast(float x, int l) {   // compile-time lane broadcast
    return __int_as_float(__builtin_amdgcn_readlane(__float_as_int(x), l));
}
// pack two floats to bf16 pair (RTNE), lo in low half
__device__ __forceinline__ unsigned pack_bf2(float lo, float hi) {
    unsigned ul = __float_as_uint(lo); ul += 0x7fffu + ((ul >> 16) & 1u);
    unsigned uh = __float_as_uint(hi); uh += 0x7fffu + ((uh >> 16) & 1u);
    return (ul >> 16) | (uh & 0xffff0000u);
}

// ---------------- CSR build ----------------
__global__ void k_hist(const int* __restrict__ dst, int* __restrict__ deg) {
    int i = blockIdx.x * blockDim.x + threadIdx.x;
    if (i < NE) atomicAdd(&deg[dst[i]], 1);
}

__global__ void k_part(const int* __restrict__ deg, int* __restrict__ part) {
    __shared__ int sm[SCAN_B];
    int b = blockIdx.x;
    int i = b * SCAN_B + threadIdx.x;
    sm[threadIdx.x] = (i < NN) ? deg[i] : 0;
    __syncthreads();
    for (int s = SCAN_B / 2; s > 0; s >>= 1) {
        if (threadIdx.x < s) sm[threadIdx.x] += sm[threadIdx.x + s];
        __syncthreads();
    }
    if (threadIdx.x == 0) part[b] = sm[0];
}

__global__ void k_scanpart(const int* __restrict__ part, int* __restrict__ partOfs) {
    __shared__ int sm[SCAN_B];
    int t = threadIdx.x;
    int own = (t < NB_SCAN) ? part[t] : 0;
    sm[t] = own;
    __syncthreads();
    for (int o = 1; o < SCAN_B; o <<= 1) {
        int v = (t >= o) ? sm[t - o] : 0;
        __syncthreads();
        sm[t] += v;
        __syncthreads();
    }
    if (t < NB_SCAN) partOfs[t] = sm[t] - own;   // exclusive
}

__global__ void k_scanfinal(const int* __restrict__ deg, const int* __restrict__ partOfs,
                            int* __restrict__ rowOfs) {
    __shared__ int sm[SCAN_B];
    int b = blockIdx.x, t = threadIdx.x;
    int i = b * SCAN_B + t;
    int d = (i < NN) ? deg[i] : 0;
    sm[t] = d;
    __syncthreads();
    for (int o = 1; o < SCAN_B; o <<= 1) {
        int v = (t >= o) ? sm[t - o] : 0;
        __syncthreads();
        sm[t] += v;
        __syncthreads();
    }
    if (i < NN) rowOfs[i] = partOfs[b] + sm[t] - d;
    if (i == 0) rowOfs[NN] = NE;
}

__global__ void k_scatter(const int* __restrict__ src, const int* __restrict__ dst,
                          const int* __restrict__ rowOfs, int* __restrict__ cur,
                          int* __restrict__ csr) {
    int i = blockIdx.x * blockDim.x + threadIdx.x;
    if (i < NE) {
        int d = dst[i];
        int p = rowOfs[d] + atomicAdd(&cur[d], 1);
        csr[p] = src[i];
    }
}

// ---- encoder: h = x @ encW + encb ; LDS-tiled, emits fp32 henc + bf16 table B0
__global__ __launch_bounds__(256) void k_enc(const float* __restrict__ x,
                                             const float* __restrict__ W,
                                             const float* __restrict__ bias,
                                             float* __restrict__ h,
                                             unsigned* __restrict__ B0) {
    __shared__ float XL[32 * INC];     // 16 KB
    __shared__ float WL[INC * HIDC];   // 32 KB
    int tid = threadIdx.x;
    for (int i = tid; i < (INC * HIDC) / 4; i += 256)
        ((float4*)WL)[i] = ((const float4*)W)[i];
    int r0 = blockIdx.x * 32;
    for (int i = tid; i < (32 * INC) / 4; i += 256) {
        int row = i >> 5;            // 32 float4 per row
        float4 val = make_float4(0.f, 0.f, 0.f, 0.f);
        if (r0 + row < NN) val = ((const float4*)x)[(size_t)(r0 + row) * 32 + (i & 31)];
        ((float4*)XL)[i] = val;
    }
    __syncthreads();
    int lane = tid & 63, w = tid >> 6;
    float bv = bias[lane];
    #pragma unroll
    for (int i = 0; i < 4; i++) {
        int ra = w * 8 + i * 2, rb = ra + 1;
        float a0 = 0.f, a1 = 0.f, a2 = 0.f, a3 = 0.f;
        float c0 = 0.f, c1 = 0.f, c2 = 0.f, c3 = 0.f;
        #pragma unroll
        for (int k = 0; k < INC; k += 4) {
            float4 xa = *(const float4*)&XL[ra * INC + k];
            float4 xb = *(const float4*)&XL[rb * INC + k];
            float w0 = WL[(k + 0) * HIDC + lane];
            float w1 = WL[(k + 1) * HIDC + lane];
            float w2 = WL[(k + 2) * HIDC + lane];
            float w3 = WL[(k + 3) * HIDC + lane];
            a0 = fmaf(xa.x, w0, a0); a1 = fmaf(xa.y, w1, a1);
            a2 = fmaf(xa.z, w2, a2); a3 = fmaf(xa.w, w3, a3);
            c0 = fmaf(xb.x, w0, c0); c1 = fmaf(xb.y, w1, c1);
            c2 = fmaf(xb.z, w2, c2); c3 = fmaf(xb.w, w3, c3);
        }
        int ga = r0 + ra, gb = r0 + rb;
        float va = bv + ((a0 + a1) + (a2 + a3));
        float vb = bv + ((c0 + c1) + (c2 + c3));
        float pa = __shfl_xor(va, 1, 64);
        float pb = __shfl_xor(vb, 1, 64);
        if (ga < NN) {
            h[(size_t)ga * HIDC + lane] = va;
            if (!(lane & 1)) B0[(size_t)ga * 32 + (lane >> 1)] = pack_bf2(va, pa);
        }
        if (gb < NN) {
            h[(size_t)gb * HIDC + lane] = vb;
            if (!(lane & 1)) B0[(size_t)gb * 32 + (lane >> 1)] = pack_bf2(vb, pb);
        }
    }
}

// ---- phase A: softmax-aggregation. one node/wave, NO LDS, max residency.
// lanes: 4 edge-subgroups x 16 channel-blocks; uint2 = 4 bf16 channels.
// writes A[v] = aggr (+ henc self for FIRST), fp32.
template<bool FIRST>
__global__ __launch_bounds__(256) void k_aggr(const float* __restrict__ henc,
                                              const unsigned* __restrict__ Bin,
                                              const int* __restrict__ rowOfs,
                                              const int* __restrict__ csr,
                                              const float* __restrict__ tptr,
                                              float* __restrict__ A) {
    int lane = threadIdx.x & 63;
    int v = (blockIdx.x * 256 + threadIdx.x) >> 6;   // [0, 50000)
    int g = lane >> 4;          // edge subgroup 0..3
    int c = lane & 15;          // channel block (channels 4c..4c+3)
    float tl = (*tptr) * 1.44269504088896f;   // t * log2(e)

    int e0 = rowOfs[v], e1 = rowOfs[v + 1];
    float se0 = 0.f, se1 = 0.f, se2 = 0.f, se3 = 0.f;
    float sw0 = 0.f, sw1 = 0.f, sw2 = 0.f, sw3 = 0.f;
    for (int e = e0; e < e1; e += 16) {
        #pragma unroll
        for (int j = 0; j < 4; j++) {
            int ee = e + 4 * j + g;
            bool valid = ee < e1;
            int s = csr[valid ? ee : e0];
            uint2 q = ((const uint2*)Bin)[(size_t)s * 16 + c];
            float g0 = __uint_as_float(q.x << 16);
            float g1 = __uint_as_float(q.x & 0xffff0000u);
            float g2 = __uint_as_float(q.y << 16);
            float g3 = __uint_as_float(q.y & 0xffff0000u);
            g0 = fmaxf(g0, 0.f) + EPS_MSG;
            g1 = fmaxf(g1, 0.f) + EPS_MSG;
            g2 = fmaxf(g2, 0.f) + EPS_MSG;
            g3 = fmaxf(g3, 0.f) + EPS_MSG;
            float w0 = valid ? exp2f(tl * g0) : 0.f;
            float w1 = valid ? exp2f(tl * g1) : 0.f;
            float w2 = valid ? exp2f(tl * g2) : 0.f;
            float w3 = valid ? exp2f(tl * g3) : 0.f;
            se0 += w0; sw0 = fmaf(g0, w0, sw0);
            se1 += w1; sw1 = fmaf(g1, w1, sw1);
            se2 += w2; sw2 = fmaf(g2, w2, sw2);
            se3 += w3; sw3 = fmaf(g3, w3, sw3);
        }
    }
    // reduce across the 4 edge-subgroups
    #pragma unroll
    for (int m = 16; m <= 32; m <<= 1) {
        se0 += __shfl_xor(se0, m, 64); sw0 += __shfl_xor(sw0, m, 64);
        se1 += __shfl_xor(se1, m, 64); sw1 += __shfl_xor(sw1, m, 64);
        se2 += __shfl_xor(se2, m, 64); sw2 += __shfl_xor(sw2, m, 64);
        se3 += __shfl_xor(se3, m, 64); sw3 += __shfl_xor(sw3, m, 64);
    }
    if (g == 0) {
        float4 r;
        r.x = sw0 / (se0 + EPS_SM);
        r.y = sw1 / (se1 + EPS_SM);
        r.z = sw2 / (se2 + EPS_SM);
        r.w = sw3 / (se3 + EPS_SM);
        if (FIRST) {
            float4 s4 = ((const float4*)henc)[(size_t)v * 16 + c];
            r.x += s4.x; r.y += s4.y; r.z += s4.z; r.w += s4.w;
        }
        ((float4*)A)[(size_t)v * 16 + c] = r;
    }
}

// ---- phase B: dense MLP row kernel. grid-stride, W staged once per block.
// LNRES: add relu(LN(h)) self + h residual. MODE 0: emit h + bf16 y table;
// MODE 1: final -> LN+relu+log_softmax into h.
template<bool LNRES, int MODE>
__global__ __launch_bounds__(256) void k_mlp(const float* __restrict__ A,
                                             float* __restrict__ h,
                                             unsigned* __restrict__ Bout,
                                             const float* __restrict__ W,
                                             const float* __restrict__ b) {
    __shared__ float WL[HIDC * HIDC];  // 16 KB
    for (int i = threadIdx.x; i < (HIDC * HIDC) / 4; i += 256)
        ((float4*)WL)[i] = ((const float4*)W)[i];
    __syncthreads();

    int lane = threadIdx.x & 63;
    int wid = (blockIdx.x * 256 + threadIdx.x) >> 6;
    int nw = (gridDim.x * 256) >> 6;
    float bv = b[lane];

    for (int v = wid; v < NN; v += nw) {
        float a = A[(size_t)v * HIDC + lane];
        float base = bv;
        if (LNRES) {
            float hv = h[(size_t)v * HIDC + lane];
            float mu = wave_sum(hv) * (1.f / 64.f);
            float d = hv - mu;
            float var = wave_sum(d * d) * (1.f / 64.f);
            a += fmaxf(d * rsqrtf(var + LN_EPS), 0.f);
            base += hv;
        }
        float a0 = 0.f, a1 = 0.f, a2 = 0.f, a3 = 0.f;
        #pragma unroll
        for (int k = 0; k < 64; k += 4) {
            a0 = fmaf(bcast(a, k + 0), WL[(k + 0) * HIDC + lane], a0);
            a1 = fmaf(bcast(a, k + 1), WL[(k + 1) * HIDC + lane], a1);
            a2 = fmaf(bcast(a, k + 2), WL[(k + 2) * HIDC + lane], a2);
            a3 = fmaf(bcast(a, k + 3), WL[(k + 3) * HIDC + lane], a3);
        }
        float acc = base + ((a0 + a1) + (a2 + a3));

        if (MODE == 1) {
            float mu = wave_sum(acc) * (1.f / 64.f);
            float d = acc - mu;
            float var = wave_sum(d * d) * (1.f / 64.f);
            float z = fmaxf(d * rsqrtf(var + LN_EPS), 0.f);
            float m = wave_max(z);
            float s2 = wave_sum(exp2f((z - m) * 1.44269504088896f));
            h[(size_t)v * HIDC + lane] = z - (m + __logf(s2));
        } else {
            h[(size_t)v * HIDC + lane] = acc;
            float mu = wave_sum(acc) * (1.f / 64.f);
            float d = acc - mu;
            float var = wave_sum(d * d) * (1.f / 64.f);
            float y = fmaxf(d * rsqrtf(var + LN_EPS), 0.f);
            float yp = __shfl_xor(y, 1, 64);
            if (!(lane & 1)) Bout[(size_t)v * 32 + (lane >> 1)] = pack_bf2(y, yp);
        }
    }
}

extern "C" void kernel_launch(void* const* d_in, const int* in_sizes, int n_in,
                              void* d_out, int out_size, void* d_ws, size_t ws_size,
                              hipStream_t stream) {
    const float* x    = (const float*)d_in[0];
    const int*   ei   = (const int*)d_in[1];
    const float* encW = (const float*)d_in[2];
    const float* encb = (const float*)d_in[3];
    const float* mlpW = (const float*)d_in[4];
    const float* mlpb = (const float*)d_in[5];
    const float* t    = (const float*)d_in[6];

    float* h = (float*)d_out;   // residual carry, doubles as final output

    char* ws = (char*)d_ws;
    size_t off = 0;
    auto alloc = [&](size_t bytes) -> void* {
        void* p = ws + off;
        off += (bytes + 255) / 256 * 256;
        return p;
    };
    float*    henc   = (float*)alloc((size_t)NN * HIDC * 4);
    float*    A      = (float*)alloc((size_t)NN * HIDC * 4);
    unsigned* B0     = (unsigned*)alloc((size_t)NN * 32 * 4);
    unsigned* B1     = (unsigned*)alloc((size_t)NN * 32 * 4);
    int*      deg    = (int*)alloc((size_t)NN * 4);
    int*      cur    = (int*)alloc((size_t)NN * 4);
    int*      rowOfs = (int*)alloc((size_t)(NN + 1) * 4);
    int*      part   = (int*)alloc((size_t)NB_SCAN * 4);
    int*      partOf = (int*)alloc((size_t)NB_SCAN * 4);
    int*      csr    = (int*)alloc((size_t)NE * 4);

    const int* src = ei;
    const int* dst = ei + NE;

    hipMemsetAsync(deg, 0, (size_t)NN * 4, stream);
    hipMemsetAsync(cur, 0, (size_t)NN * 4, stream);

    k_hist<<<(NE + 255) / 256, 256, 0, stream>>>(dst, deg);
    k_part<<<NB_SCAN, SCAN_B, 0, stream>>>(deg, part);
    k_scanpart<<<1, SCAN_B, 0, stream>>>(part, partOf);
    k_scanfinal<<<NB_SCAN, SCAN_B, 0, stream>>>(deg, partOf, rowOfs);
    k_scatter<<<(NE + 255) / 256, 256, 0, stream>>>(src, dst, rowOfs, cur, csr);

    k_enc<<<(NN + 31) / 32, 256, 0, stream>>>(x, encW, encb, henc, B0);

    // layer 0: A = aggr(B0) + henc ; h = A@W0 + b0 ; emit y -> B1
    k_aggr<true><<<12500, 256, 0, stream>>>(henc, B0, rowOfs, csr, t, A);
    k_mlp<false, 0><<<2048, 256, 0, stream>>>(A, h, B1, mlpW, mlpb);

    for (int l = 1; l < NL - 1; l++) {
        unsigned* Bi = (l & 1) ? B1 : B0;
        unsigned* Bo = (l & 1) ? B0 : B1;
        k_aggr<false><<<12500, 256, 0, stream>>>(nullptr, Bi, rowOfs, csr, t + l, A);
        k_mlp<true, 0><<<2048, 256, 0, stream>>>(A, h, Bo,
                                                 mlpW + (size_t)l * HIDC * HIDC,
                                                 mlpb + (size_t)l * HIDC);
    }
    // layer 13: final -> log_softmax into h
    k_aggr<false><<<12500, 256, 0, stream>>>(nullptr, B1, rowOfs, csr, t + (NL - 1), A);
    k_mlp<true, 1><<<2048, 256, 0, stream>>>(A, h, nullptr,
                                             mlpW + (size_t)(NL - 1) * HIDC * HIDC,
                                             mlpb + (size_t)(NL - 1) * HIDC);
}

// Round 8
// 1030.095 us; speedup vs baseline: 2.1100x; 1.0571x over previous
//
#include <hip/hip_runtime.h>

#define NN 50000
#define NE 800000
#define INC 128
#define HIDC 64
#define NL 14
#define EPS_MSG 1e-7f
#define EPS_SM 1e-16f
#define LN_EPS 1e-5f
#define LOG2E 1.44269504088896f

#define SCAN_B 256
#define NB_SCAN ((NN + SCAN_B - 1) / SCAN_B)   // 196

__device__ __forceinline__ float wave_sum(float v) {
    #pragma unroll
    for (int o = 32; o > 0; o >>= 1) v += __shfl_xor(v, o, 64);
    return v;
}
__device__ __forceinline__ float wave_max(float v) {
    #pragma unroll
    for (int o = 32; o > 0; o >>= 1) v = fmaxf(v, __shfl_xor(v, o, 64));
    return v;
}
__device__ __forceinline__ float bcast(float x, int l) {   // compile-time lane broadcast
    return __int_as_float(__builtin_amdgcn_readlane(__float_as_int(x), l));
}
// raw v_exp_f32 (2^x) — bypasses precise-libm exp2f expansion
__device__ __forceinline__ float fexp2(float x) {
    float r; asm("v_exp_f32 %0, %1" : "=v"(r) : "v"(x)); return r;
}
// pack two floats to bf16 pair (RTNE), lo in low half
__device__ __forceinline__ unsigned pack_bf2(float lo, float hi) {
    unsigned ul = __float_as_uint(lo); ul += 0x7fffu + ((ul >> 16) & 1u);
    unsigned uh = __float_as_uint(hi); uh += 0x7fffu + ((uh >> 16) & 1u);
    return (ul >> 16) | (uh & 0xffff0000u);
}

// ---------------- CSR build ----------------
__global__ void k_hist(const int* __restrict__ dst, int* __restrict__ deg) {
    int i = blockIdx.x * blockDim.x + threadIdx.x;
    if (i < NE) atomicAdd(&deg[dst[i]], 1);
}

__global__ void k_part(const int* __restrict__ deg, int* __restrict__ part) {
    __shared__ int sm[SCAN_B];
    int b = blockIdx.x;
    int i = b * SCAN_B + threadIdx.x;
    sm[threadIdx.x] = (i < NN) ? deg[i] : 0;
    __syncthreads();
    for (int s = SCAN_B / 2; s > 0; s >>= 1) {
        if (threadIdx.x < s) sm[threadIdx.x] += sm[threadIdx.x + s];
        __syncthreads();
    }
    if (threadIdx.x == 0) part[b] = sm[0];
}

__global__ void k_scanpart(const int* __restrict__ part, int* __restrict__ partOfs) {
    __shared__ int sm[SCAN_B];
    int t = threadIdx.x;
    int own = (t < NB_SCAN) ? part[t] : 0;
    sm[t] = own;
    __syncthreads();
    for (int o = 1; o < SCAN_B; o <<= 1) {
        int v = (t >= o) ? sm[t - o] : 0;
        __syncthreads();
        sm[t] += v;
        __syncthreads();
    }
    if (t < NB_SCAN) partOfs[t] = sm[t] - own;   // exclusive
}

__global__ void k_scanfinal(const int* __restrict__ deg, const int* __restrict__ partOfs,
                            int* __restrict__ rowOfs) {
    __shared__ int sm[SCAN_B];
    int b = blockIdx.x, t = threadIdx.x;
    int i = b * SCAN_B + t;
    int d = (i < NN) ? deg[i] : 0;
    sm[t] = d;
    __syncthreads();
    for (int o = 1; o < SCAN_B; o <<= 1) {
        int v = (t >= o) ? sm[t - o] : 0;
        __syncthreads();
        sm[t] += v;
        __syncthreads();
    }
    if (i < NN) rowOfs[i] = partOfs[b] + sm[t] - d;
    if (i == 0) rowOfs[NN] = NE;
}

// scatter: atomicAdd directly on rowCur (copy of rowOfs); csr stores BYTE offsets
__global__ void k_scatter(const int* __restrict__ src, const int* __restrict__ dst,
                          int* __restrict__ rowCur, int* __restrict__ csrB) {
    int i = blockIdx.x * blockDim.x + threadIdx.x;
    if (i < NE) {
        int p = atomicAdd(&rowCur[dst[i]], 1);
        csrB[p] = src[i] << 7;   // row = 128 bytes in bf16 table
    }
}

// ---- encoder: h = x @ encW + encb ; emits fp32 henc + pre-scaled bf16 table B0
// B0 stores t0*log2e*relu(enc)
__global__ __launch_bounds__(256) void k_enc(const float* __restrict__ x,
                                             const float* __restrict__ W,
                                             const float* __restrict__ bias,
                                             const float* __restrict__ tptr,
                                             float* __restrict__ h,
                                             unsigned* __restrict__ B0) {
    __shared__ float XL[32 * INC];     // 16 KB
    __shared__ float WL[INC * HIDC];   // 32 KB
    int tid = threadIdx.x;
    for (int i = tid; i < (INC * HIDC) / 4; i += 256)
        ((float4*)WL)[i] = ((const float4*)W)[i];
    int r0 = blockIdx.x * 32;
    for (int i = tid; i < (32 * INC) / 4; i += 256) {
        int row = i >> 5;            // 32 float4 per row
        float4 val = make_float4(0.f, 0.f, 0.f, 0.f);
        if (r0 + row < NN) val = ((const float4*)x)[(size_t)(r0 + row) * 32 + (i & 31)];
        ((float4*)XL)[i] = val;
    }
    __syncthreads();
    int lane = tid & 63, w = tid >> 6;
    float bv = bias[lane];
    float sc = tptr[0] * LOG2E;
    #pragma unroll
    for (int i = 0; i < 4; i++) {
        int ra = w * 8 + i * 2, rb = ra + 1;
        float a0 = 0.f, a1 = 0.f, a2 = 0.f, a3 = 0.f;
        float c0 = 0.f, c1 = 0.f, c2 = 0.f, c3 = 0.f;
        #pragma unroll
        for (int k = 0; k < INC; k += 4) {
            float4 xa = *(const float4*)&XL[ra * INC + k];
            float4 xb = *(const float4*)&XL[rb * INC + k];
            float w0 = WL[(k + 0) * HIDC + lane];
            float w1 = WL[(k + 1) * HIDC + lane];
            float w2 = WL[(k + 2) * HIDC + lane];
            float w3 = WL[(k + 3) * HIDC + lane];
            a0 = fmaf(xa.x, w0, a0); a1 = fmaf(xa.y, w1, a1);
            a2 = fmaf(xa.z, w2, a2); a3 = fmaf(xa.w, w3, a3);
            c0 = fmaf(xb.x, w0, c0); c1 = fmaf(xb.y, w1, c1);
            c2 = fmaf(xb.z, w2, c2); c3 = fmaf(xb.w, w3, c3);
        }
        int ga = r0 + ra, gb = r0 + rb;
        float va = bv + ((a0 + a1) + (a2 + a3));
        float vb = bv + ((c0 + c1) + (c2 + c3));
        float sa = sc * fmaxf(va, 0.f), sb = sc * fmaxf(vb, 0.f);
        float pa = __shfl_xor(sa, 1, 64);
        float pb = __shfl_xor(sb, 1, 64);
        if (ga < NN) {
            h[(size_t)ga * HIDC + lane] = va;
            if (!(lane & 1)) B0[(size_t)ga * 32 + (lane >> 1)] = pack_bf2(sa, pa);
        }
        if (gb < NN) {
            h[(size_t)gb * HIDC + lane] = vb;
            if (!(lane & 1)) B0[(size_t)gb * 32 + (lane >> 1)] = pack_bf2(sb, pb);
        }
    }
}

// ---- phase A: softmax-aggregation. one node/wave, no LDS.
// Table holds G = t*log2e*relu(msg): w = 2^G; mean' = sum(G*w)/sum(w);
// true aggr = mean'/(t*log2e) + EPS_MSG (eps folded out of softmax exactly).
template<bool FIRST>
__global__ __launch_bounds__(256) void k_aggr(const float* __restrict__ henc,
                                              const unsigned* __restrict__ Bin,
                                              const int* __restrict__ rowOfs,
                                              const int* __restrict__ csrB,
                                              const float* __restrict__ tptr,
                                              float* __restrict__ A) {
    int lane = threadIdx.x & 63;
    int v = (blockIdx.x * 256 + threadIdx.x) >> 6;   // [0, 50000)
    int g = lane >> 4;          // edge subgroup 0..3
    int c = lane & 15;          // channel block (channels 4c..4c+3)
    const char* basec = (const char*)Bin + (c << 3);
    float invs = 1.0f / (tptr[0] * LOG2E);

    int e0 = rowOfs[v], e1 = rowOfs[v + 1];
    float se0 = 0.f, se1 = 0.f, se2 = 0.f, se3 = 0.f;
    float sw0 = 0.f, sw1 = 0.f, sw2 = 0.f, sw3 = 0.f;
    int e = e0;
    for (; e + 16 <= e1; e += 16) {                    // full rounds: no masking
        #pragma unroll
        for (int j = 0; j < 4; j++) {
            int off = csrB[e + 4 * j + g];
            uint2 q = *(const uint2*)(basec + off);
            float g0 = __uint_as_float(q.x << 16);
            float g1 = __uint_as_float(q.x & 0xffff0000u);
            float g2 = __uint_as_float(q.y << 16);
            float g3 = __uint_as_float(q.y & 0xffff0000u);
            float w0 = fexp2(g0), w1 = fexp2(g1), w2 = fexp2(g2), w3 = fexp2(g3);
            se0 += w0; sw0 = fmaf(g0, w0, sw0);
            se1 += w1; sw1 = fmaf(g1, w1, sw1);
            se2 += w2; sw2 = fmaf(g2, w2, sw2);
            se3 += w3; sw3 = fmaf(g3, w3, sw3);
        }
    }
    if (e < e1) {                                      // masked tail round
        #pragma unroll
        for (int j = 0; j < 4; j++) {
            int ee = e + 4 * j + g;
            bool valid = ee < e1;
            int off = csrB[valid ? ee : e0];
            uint2 q = *(const uint2*)(basec + off);
            float g0 = __uint_as_float(q.x << 16);
            float g1 = __uint_as_float(q.x & 0xffff0000u);
            float g2 = __uint_as_float(q.y << 16);
            float g3 = __uint_as_float(q.y & 0xffff0000u);
            float w0 = valid ? fexp2(g0) : 0.f;
            float w1 = valid ? fexp2(g1) : 0.f;
            float w2 = valid ? fexp2(g2) : 0.f;
            float w3 = valid ? fexp2(g3) : 0.f;
            se0 += w0; sw0 = fmaf(g0, w0, sw0);
            se1 += w1; sw1 = fmaf(g1, w1, sw1);
            se2 += w2; sw2 = fmaf(g2, w2, sw2);
            se3 += w3; sw3 = fmaf(g3, w3, sw3);
        }
    }
    // reduce across the 4 edge-subgroups
    #pragma unroll
    for (int m = 16; m <= 32; m <<= 1) {
        se0 += __shfl_xor(se0, m, 64); sw0 += __shfl_xor(sw0, m, 64);
        se1 += __shfl_xor(se1, m, 64); sw1 += __shfl_xor(sw1, m, 64);
        se2 += __shfl_xor(se2, m, 64); sw2 += __shfl_xor(sw2, m, 64);
        se3 += __shfl_xor(se3, m, 64); sw3 += __shfl_xor(sw3, m, 64);
    }
    if (g == 0) {
        float4 r;
        r.x = sw0 / (se0 + EPS_SM) * invs + EPS_MSG;
        r.y = sw1 / (se1 + EPS_SM) * invs + EPS_MSG;
        r.z = sw2 / (se2 + EPS_SM) * invs + EPS_MSG;
        r.w = sw3 / (se3 + EPS_SM) * invs + EPS_MSG;
        if (FIRST) {
            float4 s4 = ((const float4*)henc)[(size_t)v * 16 + c];
            r.x += s4.x; r.y += s4.y; r.z += s4.z; r.w += s4.w;
        }
        ((float4*)A)[(size_t)v * 16 + c] = r;
    }
}

// ---- phase B: dense MLP row kernel. grid-stride, W staged once per block.
// LNRES: add relu(LN(h)) self + h residual. MODE 0: emit h + pre-scaled bf16 y
// table (t_next*log2e*y); MODE 1: final -> LN+relu+log_softmax into h.
template<bool LNRES, int MODE>
__global__ __launch_bounds__(256) void k_mlp(const float* __restrict__ A,
                                             float* __restrict__ h,
                                             unsigned* __restrict__ Bout,
                                             const float* __restrict__ W,
                                             const float* __restrict__ b,
                                             const float* __restrict__ tnext) {
    __shared__ float WL[HIDC * HIDC];  // 16 KB
    for (int i = threadIdx.x; i < (HIDC * HIDC) / 4; i += 256)
        ((float4*)WL)[i] = ((const float4*)W)[i];
    __syncthreads();

    int lane = threadIdx.x & 63;
    int wid = (blockIdx.x * 256 + threadIdx.x) >> 6;
    int nw = (gridDim.x * 256) >> 6;
    float bv = b[lane];
    float sc = (MODE == 0) ? tnext[0] * LOG2E : 0.f;

    for (int v = wid; v < NN; v += nw) {
        float a = A[(size_t)v * HIDC + lane];
        float base = bv;
        if (LNRES) {
            float hv = h[(size_t)v * HIDC + lane];
            float mu = wave_sum(hv) * (1.f / 64.f);
            float d = hv - mu;
            float var = wave_sum(d * d) * (1.f / 64.f);
            a += fmaxf(d * rsqrtf(var + LN_EPS), 0.f);
            base += hv;
        }
        float a0 = 0.f, a1 = 0.f, a2 = 0.f, a3 = 0.f;
        #pragma unroll
        for (int k = 0; k < 64; k += 4) {
            a0 = fmaf(bcast(a, k + 0), WL[(k + 0) * HIDC + lane], a0);
            a1 = fmaf(bcast(a, k + 1), WL[(k + 1) * HIDC + lane], a1);
            a2 = fmaf(bcast(a, k + 2), WL[(k + 2) * HIDC + lane], a2);
            a3 = fmaf(bcast(a, k + 3), WL[(k + 3) * HIDC + lane], a3);
        }
        float acc = base + ((a0 + a1) + (a2 + a3));

        if (MODE == 1) {
            float mu = wave_sum(acc) * (1.f / 64.f);
            float d = acc - mu;
            float var = wave_sum(d * d) * (1.f / 64.f);
            float z = fmaxf(d * rsqrtf(var + LN_EPS), 0.f);
            float m = wave_max(z);
            float s2 = wave_sum(fexp2((z - m) * LOG2E));
            h[(size_t)v * HIDC + lane] = z - (m + __logf(s2));
        } else {
            h[(size_t)v * HIDC + lane] = acc;
            float mu = wave_sum(acc) * (1.f / 64.f);
            float d = acc - mu;
            float var = wave_sum(d * d) * (1.f / 64.f);
            float y = sc * fmaxf(d * rsqrtf(var + LN_EPS), 0.f);
            float yp = __shfl_xor(y, 1, 64);
            if (!(lane & 1)) Bout[(size_t)v * 32 + (lane >> 1)] = pack_bf2(y, yp);
        }
    }
}

extern "C" void kernel_launch(void* const* d_in, const int* in_sizes, int n_in,
                              void* d_out, int out_size, void* d_ws, size_t ws_size,
                              hipStream_t stream) {
    const float* x    = (const float*)d_in[0];
    const int*   ei   = (const int*)d_in[1];
    const float* encW = (const float*)d_in[2];
    const float* encb = (const float*)d_in[3];
    const float* mlpW = (const float*)d_in[4];
    const float* mlpb = (const float*)d_in[5];
    const float* t    = (const float*)d_in[6];

    float* h = (float*)d_out;   // residual carry, doubles as final output

    char* ws = (char*)d_ws;
    size_t off = 0;
    auto alloc = [&](size_t bytes) -> void* {
        void* p = ws + off;
        off += (bytes + 255) / 256 * 256;
        return p;
    };
    float*    henc   = (float*)alloc((size_t)NN * HIDC * 4);
    float*    A      = (float*)alloc((size_t)NN * HIDC * 4);
    unsigned* B0     = (unsigned*)alloc((size_t)NN * 32 * 4);
    unsigned* B1     = (unsigned*)alloc((size_t)NN * 32 * 4);
    int*      deg    = (int*)alloc((size_t)NN * 4);
    int*      rowOfs = (int*)alloc((size_t)(NN + 1) * 4);
    int*      rowCur = (int*)alloc((size_t)NN * 4);
    int*      part   = (int*)alloc((size_t)NB_SCAN * 4);
    int*      partOf = (int*)alloc((size_t)NB_SCAN * 4);
    int*      csrB   = (int*)alloc((size_t)NE * 4);

    const int* src = ei;
    const int* dst = ei + NE;

    hipMemsetAsync(deg, 0, (size_t)NN * 4, stream);

    k_hist<<<(NE + 255) / 256, 256, 0, stream>>>(dst, deg);
    k_part<<<NB_SCAN, SCAN_B, 0, stream>>>(deg, part);
    k_scanpart<<<1, SCAN_B, 0, stream>>>(part, partOf);
    k_scanfinal<<<NB_SCAN, SCAN_B, 0, stream>>>(deg, partOf, rowOfs);
    hipMemcpyAsync(rowCur, rowOfs, (size_t)NN * 4, hipMemcpyDeviceToDevice, stream);
    k_scatter<<<(NE + 255) / 256, 256, 0, stream>>>(src, dst, rowCur, csrB);

    k_enc<<<(NN + 31) / 32, 256, 0, stream>>>(x, encW, encb, t, henc, B0);

    // layer 0: A = aggr(B0) + henc ; h = A@W0 + b0 ; emit y table -> B1 (scaled t1)
    k_aggr<true><<<12500, 256, 0, stream>>>(henc, B0, rowOfs, csrB, t, A);
    k_mlp<false, 0><<<2048, 256, 0, stream>>>(A, h, B1, mlpW, mlpb, t + 1);

    for (int l = 1; l < NL - 1; l++) {
        unsigned* Bi = (l & 1) ? B1 : B0;
        unsigned* Bo = (l & 1) ? B0 : B1;
        k_aggr<false><<<12500, 256, 0, stream>>>(nullptr, Bi, rowOfs, csrB, t + l, A);
        k_mlp<true, 0><<<2048, 256, 0, stream>>>(A, h, Bo,
                                                 mlpW + (size_t)l * HIDC * HIDC,
                                                 mlpb + (size_t)l * HIDC, t + l + 1);
    }
    // layer 13: final -> log_softmax into h
    k_aggr<false><<<12500, 256, 0, stream>>>(nullptr, B1, rowOfs, csrB, t + (NL - 1), A);
    k_mlp<true, 1><<<2048, 256, 0, stream>>>(A, h, nullptr,
                                             mlpW + (size_t)(NL - 1) * HIDC * HIDC,
                                             mlpb + (size_t)(NL - 1) * HIDC, nullptr);
}